// Round 7
// baseline (225.117 us; speedup 1.0000x reference)
//
#include <hip/hip_runtime.h>

#define BB 8
#define NN 4096
#define LL 4096
#define CC 256

typedef short bf16x8 __attribute__((ext_vector_type(8)));
typedef _Float16 f16x8 __attribute__((ext_vector_type(8)));
typedef __fp16 hf16x2 __attribute__((ext_vector_type(2)));  // cvt_pkrtz return type
typedef float f32x4 __attribute__((ext_vector_type(4)));

__device__ __forceinline__ short f2bf(float f) {
  union { float f; unsigned u; } v; v.f = f;
  unsigned r = v.u + 0x7fffu + ((v.u >> 16) & 1u);
  return (short)(r >> 16);
}
// 8 consecutive f32 -> bf16x8 MFMA fragment (two float4 loads)
__device__ __forceinline__ bf16x8 ld8(const float* __restrict__ fp) {
  float4 a = *(const float4*)fp;
  float4 b = *(const float4*)(fp + 4);
  bf16x8 r;
  r[0] = f2bf(a.x); r[1] = f2bf(a.y); r[2] = f2bf(a.z); r[3] = f2bf(a.w);
  r[4] = f2bf(b.x); r[5] = f2bf(b.y); r[6] = f2bf(b.z); r[7] = f2bf(b.w);
  return r;
}

// ---------------------------------------------------------------------------
// Kernel A: projections (f32 inputs).  Also zeroes Zbuf (kb1 atomics target).
// ---------------------------------------------------------------------------
__global__ __launch_bounds__(256) void ka_proj(
    const float* __restrict__ graph, const float* __restrict__ img,
    const float* __restrict__ Wq, const float* __restrict__ bq,
    const float* __restrict__ Wk, const float* __restrict__ bk,
    const float* __restrict__ Wv, const float* __restrict__ bv,
    short* __restrict__ Qb, short* __restrict__ Kt, _Float16* __restrict__ Vt,
    float* __restrict__ Zbuf)
{
  const int tid = threadIdx.x;
  const int w = tid >> 6, lane = tid & 63, lo = lane & 15, q = lane >> 4;
  const int bid = blockIdx.x;
  if (bid < 512) {
    const int b = bid >> 6;
    if (tid < 64) Zbuf[(size_t)b * LL + ((bid & 63) << 6) + tid] = 0.0f;
    const int lt = ((bid & 63) << 6) + (w << 4);
    f32x4 aK0 = {0,0,0,0}, aK1 = {0,0,0,0}, aV0 = {0,0,0,0}, aV1 = {0,0,0,0};
    const float* ib = img + (size_t)b * CC * LL + lt + lo;
    #pragma unroll
    for (int cs = 0; cs < 8; ++cs) {
      const int c0 = cs * 32 + q * 8;
      bf16x8 bi;
      #pragma unroll
      for (int j = 0; j < 8; ++j) bi[j] = f2bf(ib[(size_t)(c0 + j) * LL]);
      bf16x8 wk0 = ld8(Wk + lo * CC + c0);
      bf16x8 wk1 = ld8(Wk + (lo + 16) * CC + c0);
      bf16x8 wv0 = ld8(Wv + lo * CC + c0);
      bf16x8 wv1 = ld8(Wv + (lo + 16) * CC + c0);
      aK0 = __builtin_amdgcn_mfma_f32_16x16x32_bf16(wk0, bi, aK0, 0, 0, 0);
      aK1 = __builtin_amdgcn_mfma_f32_16x16x32_bf16(wk1, bi, aK1, 0, 0, 0);
      aV0 = __builtin_amdgcn_mfma_f32_16x16x32_bf16(wv0, bi, aV0, 0, 0, 0);
      aV1 = __builtin_amdgcn_mfma_f32_16x16x32_bf16(wv1, bi, aV1, 0, 0, 0);
    }
    const float kscale = 0.2550348663f;   // log2(e)/sqrt(32)
    const size_t row = ((size_t)b * LL + lt + lo) * 32;
    short4 s0, s1;
    s0.x = f2bf((aK0[0] + bk[q * 4 + 0]) * kscale);
    s0.y = f2bf((aK0[1] + bk[q * 4 + 1]) * kscale);
    s0.z = f2bf((aK0[2] + bk[q * 4 + 2]) * kscale);
    s0.w = f2bf((aK0[3] + bk[q * 4 + 3]) * kscale);
    s1.x = f2bf((aK1[0] + bk[16 + q * 4 + 0]) * kscale);
    s1.y = f2bf((aK1[1] + bk[16 + q * 4 + 1]) * kscale);
    s1.z = f2bf((aK1[2] + bk[16 + q * 4 + 2]) * kscale);
    s1.w = f2bf((aK1[3] + bk[16 + q * 4 + 3]) * kscale);
    *(short4*)(Kt + row + q * 4) = s0;
    *(short4*)(Kt + row + 16 + q * 4) = s1;
    union { hf16x2 h[2]; uint2 u; } p0, p1;
    p0.h[0] = __builtin_amdgcn_cvt_pkrtz(aV0[0] + bv[q * 4 + 0], aV0[1] + bv[q * 4 + 1]);
    p0.h[1] = __builtin_amdgcn_cvt_pkrtz(aV0[2] + bv[q * 4 + 2], aV0[3] + bv[q * 4 + 3]);
    p1.h[0] = __builtin_amdgcn_cvt_pkrtz(aV1[0] + bv[16 + q * 4 + 0], aV1[1] + bv[16 + q * 4 + 1]);
    p1.h[1] = __builtin_amdgcn_cvt_pkrtz(aV1[2] + bv[16 + q * 4 + 2], aV1[3] + bv[16 + q * 4 + 3]);
    *(uint2*)(Vt + row + q * 4) = p0.u;
    *(uint2*)(Vt + row + 16 + q * 4) = p1.u;
  } else {
    const int t = bid - 512;
    const int b = t >> 6;
    const int nt = ((t & 63) << 6) + (w << 4);
    bf16x8 ag = ld8(graph + ((size_t)b * NN + nt + lo) * 32 + q * 8);
    bf16x8 w0 = ld8(Wq + lo * 32 + q * 8);
    bf16x8 w1 = ld8(Wq + (lo + 16) * 32 + q * 8);
    f32x4 z = {0,0,0,0};
    f32x4 a0 = __builtin_amdgcn_mfma_f32_16x16x32_bf16(ag, w0, z, 0, 0, 0);
    f32x4 a1 = __builtin_amdgcn_mfma_f32_16x16x32_bf16(ag, w1, z, 0, 0, 0);
    const float b0 = bq[lo], b1 = bq[lo + 16];
    #pragma unroll
    for (int r = 0; r < 4; ++r) {
      const size_t rowq = ((size_t)b * NN + nt + q * 4 + r) * 32;
      Qb[rowq + lo] = f2bf(a0[r] + b0);
      Qb[rowq + 16 + lo] = f2bf(a1[r] + b1);
    }
  }
}

// ---------------------------------------------------------------------------
// Kernel B1: partial softmax denominators.  2048 blocks x 4 waves.
// Wave: 64 l x 256 n as TWO independent 128-n streams (za/zb accumulators,
// shared K frags) for ILP; Q frags prefetched.  Z += sum_n exp2 (atomicAdd).
// ---------------------------------------------------------------------------
__global__ __launch_bounds__(256, 6) void kb1_z(
    const short* __restrict__ Qb, const short* __restrict__ Kt,
    float* __restrict__ Z)
{
  const int tid = threadIdx.x;
  const int w = tid >> 6, lane = tid & 63, lo = lane & 15, q = lane >> 4;
  const int bid = blockIdx.x;
  const int b = bid >> 8;
  const int l0 = ((bid >> 2) & 63) << 6;
  const int nq = bid & 3;
  bf16x8 kf[4];
  #pragma unroll
  for (int f = 0; f < 4; ++f)
    kf[f] = *(const bf16x8*)(Kt + ((size_t)b * LL + l0 + f * 16 + lo) * 32 + q * 8);
  float za[4][4] = {{0}}, zb[4][4] = {{0}};
  const short* qbase = Qb + ((size_t)b * NN + nq * 1024 + w * 256 + lo) * 32 + q * 8;
  bf16x8 qa = *(const bf16x8*)qbase;
  bf16x8 qb = *(const bf16x8*)(qbase + 8 * 512);
  #pragma unroll
  for (int it = 0; it < 8; ++it) {
    const int itn = (it + 1 < 8) ? it + 1 : it;
    bf16x8 qan = *(const bf16x8*)(qbase + itn * 512);
    bf16x8 qbn = *(const bf16x8*)(qbase + (8 + itn) * 512);
    #pragma unroll
    for (int f = 0; f < 4; ++f) {
      f32x4 z = {0,0,0,0};
      f32x4 ca = __builtin_amdgcn_mfma_f32_16x16x32_bf16(kf[f], qa, z, 0, 0, 0);
      f32x4 cb = __builtin_amdgcn_mfma_f32_16x16x32_bf16(kf[f], qb, z, 0, 0, 0);
      #pragma unroll
      for (int r = 0; r < 4; ++r) {
        za[f][r] += __builtin_amdgcn_exp2f(ca[r]);
        zb[f][r] += __builtin_amdgcn_exp2f(cb[r]);
      }
    }
    qa = qan; qb = qbn;
  }
  #pragma unroll
  for (int f = 0; f < 4; ++f)
    #pragma unroll
    for (int r = 0; r < 4; ++r)
      za[f][r] += zb[f][r];
  // reduce over n (= lo, low 4 lane bits)
  #pragma unroll
  for (int m = 1; m < 16; m <<= 1)
    #pragma unroll
    for (int f = 0; f < 4; ++f)
      #pragma unroll
      for (int r = 0; r < 4; ++r)
        za[f][r] += __shfl_xor(za[f][r], m, 64);
  if (lo == 0) {
    #pragma unroll
    for (int f = 0; f < 4; ++f)
      #pragma unroll
      for (int r = 0; r < 4; ++r)
        atomicAdd(&Z[(size_t)b * LL + l0 + f * 16 + q * 4 + r], za[f][r]);
  }
}

// ---------------------------------------------------------------------------
// Kernel B2: Vpp[b][o][l] = Vt[b][l][o] * (4096 / Z_l)  (f16, [o][l] layout).
// ---------------------------------------------------------------------------
__global__ __launch_bounds__(256) void kb2_scale(
    const _Float16* __restrict__ Vt, const float* __restrict__ Z,
    _Float16* __restrict__ Vpp)
{
  const int tid = threadIdx.x;
  const int b = blockIdx.x >> 6;
  const int l = ((blockIdx.x & 63) << 6) + (tid & 63);
  const int og = tid >> 6;  // 0..3
  const float inv = __builtin_amdgcn_rcpf(Z[(size_t)b * LL + l]) * 4096.0f;
  const f16x8 vv = *(const f16x8*)(Vt + ((size_t)b * LL + l) * 32 + og * 8);
  #pragma unroll
  for (int j = 0; j < 8; ++j)
    Vpp[((size_t)b * 32 + og * 8 + j) * LL + l] = (_Float16)((float)vv[j] * inv);
}

// --------------------------- kc1 helpers -----------------------------------
__device__ __forceinline__ void load_kf(bf16x8 kf[4], const short* __restrict__ ktb,
                                        int lc) {
  #pragma unroll
  for (int f = 0; f < 4; ++f)
    kf[f] = *(const bf16x8*)(ktb + (size_t)(lc * 64 + f * 16) * 32);
}
__device__ __forceinline__ void load_v(f16x8 v[4], const _Float16* __restrict__ vb0,
                                       const _Float16* __restrict__ vb1, int lc, int q) {
  const int lbase = lc * 64;
  v[0] = *(const f16x8*)(vb0 + lbase + q * 8);
  v[1] = *(const f16x8*)(vb0 + lbase + 32 + q * 8);
  v[2] = *(const f16x8*)(vb1 + lbase + q * 8);
  v[3] = *(const f16x8*)(vb1 + lbase + 32 + q * 8);
}
__device__ __forceinline__ void compute_P(const bf16x8 kf[4], bf16x8 qf0, bf16x8 qf1,
                                          _Float16* __restrict__ Pb, int lo, int q) {
  #pragma unroll
  for (int f = 0; f < 4; ++f) {
    f32x4 z = {0,0,0,0};
    f32x4 c0 = __builtin_amdgcn_mfma_f32_16x16x32_bf16(kf[f], qf0, z, 0, 0, 0);
    f32x4 c1 = __builtin_amdgcn_mfma_f32_16x16x32_bf16(kf[f], qf1, z, 0, 0, 0);
    union { hf16x2 h[2]; uint2 u; } pk0, pk1;
    pk0.h[0] = __builtin_amdgcn_cvt_pkrtz(__builtin_amdgcn_exp2f(c0[0]),
                                          __builtin_amdgcn_exp2f(c0[1]));
    pk0.h[1] = __builtin_amdgcn_cvt_pkrtz(__builtin_amdgcn_exp2f(c0[2]),
                                          __builtin_amdgcn_exp2f(c0[3]));
    pk1.h[0] = __builtin_amdgcn_cvt_pkrtz(__builtin_amdgcn_exp2f(c1[0]),
                                          __builtin_amdgcn_exp2f(c1[1]));
    pk1.h[1] = __builtin_amdgcn_cvt_pkrtz(__builtin_amdgcn_exp2f(c1[2]),
                                          __builtin_amdgcn_exp2f(c1[3]));
    *(uint2*)&Pb[lo * 72 + f * 16 + q * 4] = pk0.u;
    *(uint2*)&Pb[(16 + lo) * 72 + f * 16 + q * 4] = pk1.u;
  }
}

// ---------------------------------------------------------------------------
// Kernel C1: message partials.  2048 blocks = (b, l-half, 32 n); wave covers
// 8 chunks of 64 l with a 2-stage pipeline over DOUBLE-BUFFERED per-wave P
// regions: read P[i] (buf i&1) -> prefetch -> compute P[i+1] (other buf,
// hides the ds_read latency) -> f16 MFMA chunk i.  Removes the single-buffer
// write->read->write serialization that bound R5/R6.
// LDS 36.9 KB -> 4 blk/CU; launch_bounds(256,4) caps VGPR at 128.
// ---------------------------------------------------------------------------
__global__ __launch_bounds__(256, 4) void kc1_attn(
    const short* __restrict__ Qb, const short* __restrict__ Kt,
    const _Float16* __restrict__ Vpp, float* __restrict__ msgpart)
{
  __shared__ __align__(16) unsigned char smem[36864];   // 4 waves x 2 x 4608
  const int tid = threadIdx.x;
  const int w = tid >> 6, lane = tid & 63, lo = lane & 15, q = lane >> 4;
  const int bid = blockIdx.x;
  const int b = bid >> 8;
  const int half = (bid >> 7) & 1;
  const int n0 = (bid & 127) << 5;
  _Float16* const Pb0 = (_Float16*)(smem + w * 9216);
  _Float16* const Pb1 = Pb0 + 32 * 72;
  const bf16x8 qf0 = *(const bf16x8*)(Qb + ((size_t)b * NN + n0 + lo) * 32 + q * 8);
  const bf16x8 qf1 = *(const bf16x8*)(Qb + ((size_t)b * NN + n0 + 16 + lo) * 32 + q * 8);
  f32x4 m00 = {0,0,0,0}, m01 = {0,0,0,0}, m10 = {0,0,0,0}, m11 = {0,0,0,0};
  const short* ktb = Kt + (size_t)b * LL * 32 + lo * 32 + q * 8;
  const _Float16* vb0 = Vpp + ((size_t)b * 32 + lo) * LL;
  const _Float16* vb1 = vb0 + (size_t)16 * LL;
  const int lc0 = half * 32 + w * 8;
  bf16x8 kfs[2][4];
  load_kf(kfs[0], ktb, lc0);
  load_kf(kfs[1], ktb, lc0 + 1);
  compute_P(kfs[0], qf0, qf1, Pb0, lo, q);   // P[0] -> buf0
  #pragma unroll
  for (int i = 0; i < 8; ++i) {
    _Float16* const bufC = (i & 1) ? Pb1 : Pb0;
    _Float16* const bufN = (i & 1) ? Pb0 : Pb1;
    // 1) A-fragment reads for chunk i (latency hidden by step 3)
    f16x8 pa00 = *(const f16x8*)&bufC[lo * 72 + q * 8];
    f16x8 pa01 = *(const f16x8*)&bufC[lo * 72 + 32 + q * 8];
    f16x8 pa10 = *(const f16x8*)&bufC[(16 + lo) * 72 + q * 8];
    f16x8 pa11 = *(const f16x8*)&bufC[(16 + lo) * 72 + 32 + q * 8];
    // 2) global prefetches: V for this chunk, Kt for chunk i+2
    f16x8 vc[4];
    load_v(vc, vb0, vb1, lc0 + i, q);
    if (i + 2 <= 7) load_kf(kfs[i & 1], ktb, lc0 + i + 2);
    // 3) compute P[i+1] into the other buffer (long issue stream)
    if (i + 1 <= 7) compute_P(kfs[1 - (i & 1)], qf0, qf1, bufN, lo, q);
    // 4) message MFMAs for chunk i
    m00 = __builtin_amdgcn_mfma_f32_16x16x32_f16(pa00, vc[0], m00, 0, 0, 0);
    m10 = __builtin_amdgcn_mfma_f32_16x16x32_f16(pa10, vc[0], m10, 0, 0, 0);
    m01 = __builtin_amdgcn_mfma_f32_16x16x32_f16(pa00, vc[2], m01, 0, 0, 0);
    m11 = __builtin_amdgcn_mfma_f32_16x16x32_f16(pa10, vc[2], m11, 0, 0, 0);
    m00 = __builtin_amdgcn_mfma_f32_16x16x32_f16(pa01, vc[1], m00, 0, 0, 0);
    m10 = __builtin_amdgcn_mfma_f32_16x16x32_f16(pa11, vc[1], m10, 0, 0, 0);
    m01 = __builtin_amdgcn_mfma_f32_16x16x32_f16(pa01, vc[3], m01, 0, 0, 0);
    m11 = __builtin_amdgcn_mfma_f32_16x16x32_f16(pa11, vc[3], m11, 0, 0, 0);
  }
  // stash msg partials into this wave's own P region (its P reads are done)
  float* MSw = (float*)(smem + w * 9216);   // [32 n][36]
  #pragma unroll
  for (int r = 0; r < 4; ++r) {
    MSw[(q * 4 + r) * 36 + lo] = m00[r];
    MSw[(q * 4 + r) * 36 + 16 + lo] = m01[r];
    MSw[(16 + q * 4 + r) * 36 + lo] = m10[r];
    MSw[(16 + q * 4 + r) * 36 + 16 + lo] = m11[r];
  }
  __syncthreads();
  // block-reduce the 4 wave partials, store 32x32 f32 tile (no atomics)
  const int nl = tid >> 3, oq = (tid & 7) << 2;
  f32x4 s = *(const f32x4*)((float*)(smem + 0 * 9216) + nl * 36 + oq);
  s += *(const f32x4*)((float*)(smem + 1 * 9216) + nl * 36 + oq);
  s += *(const f32x4*)((float*)(smem + 2 * 9216) + nl * 36 + oq);
  s += *(const f32x4*)((float*)(smem + 3 * 9216) + nl * 36 + oq);
  *(f32x4*)(msgpart + (((size_t)half * BB + b) * NN + n0 + nl) * 32 + oq) = s;
}

// ---------------------------------------------------------------------------
// Kernel C2: out[b][n][o] = graph + bc[o] + (Wc @ (mp0+mp1)[n])/4096.
// ---------------------------------------------------------------------------
__global__ __launch_bounds__(256) void kc2_out(
    const float* __restrict__ msgpart, const float* __restrict__ graph,
    const float* __restrict__ Wc, const float* __restrict__ bc,
    float* __restrict__ out)
{
  const int tid = threadIdx.x;
  const int b = blockIdx.x >> 7;
  const int n = ((blockIdx.x & 127) << 5) + (tid >> 3);
  const int oq = (tid & 7) << 2;
  const float* mp0 = msgpart + ((size_t)b * NN + n) * 32;
  const float* mp1 = msgpart + ((size_t)(BB + b) * NN + n) * 32;
  float m[32];
  #pragma unroll
  for (int c4 = 0; c4 < 8; ++c4) {
    f32x4 a = *(const f32x4*)(mp0 + c4 * 4);
    f32x4 bsum = *(const f32x4*)(mp1 + c4 * 4);
    f32x4 s = a + bsum;
    m[c4 * 4 + 0] = s[0]; m[c4 * 4 + 1] = s[1];
    m[c4 * 4 + 2] = s[2]; m[c4 * 4 + 3] = s[3];
  }
  #pragma unroll
  for (int j = 0; j < 4; ++j) {
    const int o = oq + j;
    float acc = 0.0f;
    #pragma unroll
    for (int c4 = 0; c4 < 8; ++c4) {
      f32x4 wv = *(const f32x4*)(Wc + o * 32 + c4 * 4);
      acc += wv[0] * m[c4 * 4 + 0] + wv[1] * m[c4 * 4 + 1]
           + wv[2] * m[c4 * 4 + 2] + wv[3] * m[c4 * 4 + 3];
    }
    const size_t idx = ((size_t)b * NN + n) * 32 + o;
    out[idx] = acc * (1.0f / 4096.0f) + bc[o] + graph[idx];
  }
}

// ---------------------------------------------------------------------------
extern "C" void kernel_launch(void* const* d_in, const int* in_sizes, int n_in,
                              void* d_out, int out_size, void* d_ws, size_t ws_size,
                              hipStream_t stream) {
  const float* graph = (const float*)d_in[0];
  const float* img   = (const float*)d_in[1];
  const float* Wq    = (const float*)d_in[2];
  const float* bq    = (const float*)d_in[3];
  const float* Wk    = (const float*)d_in[4];
  const float* bk    = (const float*)d_in[5];
  const float* Wv    = (const float*)d_in[6];
  const float* bv    = (const float*)d_in[7];
  const float* Wc    = (const float*)d_in[8];
  const float* bc    = (const float*)d_in[9];
  char* ws = (char*)d_ws;
  short*    Qb  = (short*)(ws + 0);          // 2 MB   bf16 [B][N][32]
  short*    Kt  = (short*)(ws + 2097152);    // 2 MB   bf16 [B][L][32] (scaled)
  _Float16* Vt  = (_Float16*)(ws + 4194304); // 2 MB   f16  [B][L][32]
  _Float16* Vpp = (_Float16*)(ws + 6291456); // 2 MB   f16  [B][32][L] (V*4096/Z)
  float*    Zb  = (float*)(ws + 8388608);    // 128 KB f32  [B][L]
  float*    Mp  = (float*)(ws + 8519680);    // 8 MB   f32  [2][B][N][32]
  ka_proj<<<dim3(1024), dim3(256), 0, stream>>>(graph, img, Wq, bq, Wk, bk, Wv, bv,
                                                Qb, Kt, Vt, Zb);
  kb1_z<<<dim3(2048), dim3(256), 0, stream>>>(Qb, Kt, Zb);
  kb2_scale<<<dim3(512), dim3(256), 0, stream>>>(Vt, Zb, Vpp);
  kc1_attn<<<dim3(2048), dim3(256), 0, stream>>>(Qb, Kt, Vpp, Mp);
  kc2_out<<<dim3(1024), dim3(256), 0, stream>>>(Mp, graph, Wc, bc, (float*)d_out);
}

// Round 8
// 192.276 us; speedup vs baseline: 1.1708x; 1.1708x over previous
//
#include <hip/hip_runtime.h>

#define BB 8
#define NN 4096
#define LL 4096
#define CC 256

typedef short bf16x8 __attribute__((ext_vector_type(8)));
typedef _Float16 f16x8 __attribute__((ext_vector_type(8)));
typedef __fp16 hf16x2 __attribute__((ext_vector_type(2)));  // cvt_pkrtz return type
typedef float f32x4 __attribute__((ext_vector_type(4)));

__device__ __forceinline__ short f2bf(float f) {
  union { float f; unsigned u; } v; v.f = f;
  unsigned r = v.u + 0x7fffu + ((v.u >> 16) & 1u);
  return (short)(r >> 16);
}
// 8 consecutive f32 -> bf16x8 MFMA fragment (two float4 loads)
__device__ __forceinline__ bf16x8 ld8(const float* __restrict__ fp) {
  float4 a = *(const float4*)fp;
  float4 b = *(const float4*)(fp + 4);
  bf16x8 r;
  r[0] = f2bf(a.x); r[1] = f2bf(a.y); r[2] = f2bf(a.z); r[3] = f2bf(a.w);
  r[4] = f2bf(b.x); r[5] = f2bf(b.y); r[6] = f2bf(b.z); r[7] = f2bf(b.w);
  return r;
}

// ---------------------------------------------------------------------------
// Kernel A: projections (f32 inputs).  Also zeroes Zbuf (kb1 atomics target).
// ---------------------------------------------------------------------------
__global__ __launch_bounds__(256) void ka_proj(
    const float* __restrict__ graph, const float* __restrict__ img,
    const float* __restrict__ Wq, const float* __restrict__ bq,
    const float* __restrict__ Wk, const float* __restrict__ bk,
    const float* __restrict__ Wv, const float* __restrict__ bv,
    short* __restrict__ Qb, short* __restrict__ Kt, _Float16* __restrict__ Vt,
    float* __restrict__ Zbuf)
{
  const int tid = threadIdx.x;
  const int w = tid >> 6, lane = tid & 63, lo = lane & 15, q = lane >> 4;
  const int bid = blockIdx.x;
  if (bid < 512) {
    const int b = bid >> 6;
    if (tid < 64) Zbuf[(size_t)b * LL + ((bid & 63) << 6) + tid] = 0.0f;
    const int lt = ((bid & 63) << 6) + (w << 4);
    f32x4 aK0 = {0,0,0,0}, aK1 = {0,0,0,0}, aV0 = {0,0,0,0}, aV1 = {0,0,0,0};
    const float* ib = img + (size_t)b * CC * LL + lt + lo;
    #pragma unroll
    for (int cs = 0; cs < 8; ++cs) {
      const int c0 = cs * 32 + q * 8;
      bf16x8 bi;
      #pragma unroll
      for (int j = 0; j < 8; ++j) bi[j] = f2bf(ib[(size_t)(c0 + j) * LL]);
      bf16x8 wk0 = ld8(Wk + lo * CC + c0);
      bf16x8 wk1 = ld8(Wk + (lo + 16) * CC + c0);
      bf16x8 wv0 = ld8(Wv + lo * CC + c0);
      bf16x8 wv1 = ld8(Wv + (lo + 16) * CC + c0);
      aK0 = __builtin_amdgcn_mfma_f32_16x16x32_bf16(wk0, bi, aK0, 0, 0, 0);
      aK1 = __builtin_amdgcn_mfma_f32_16x16x32_bf16(wk1, bi, aK1, 0, 0, 0);
      aV0 = __builtin_amdgcn_mfma_f32_16x16x32_bf16(wv0, bi, aV0, 0, 0, 0);
      aV1 = __builtin_amdgcn_mfma_f32_16x16x32_bf16(wv1, bi, aV1, 0, 0, 0);
    }
    const float kscale = 0.2550348663f;   // log2(e)/sqrt(32)
    const size_t row = ((size_t)b * LL + lt + lo) * 32;
    short4 s0, s1;
    s0.x = f2bf((aK0[0] + bk[q * 4 + 0]) * kscale);
    s0.y = f2bf((aK0[1] + bk[q * 4 + 1]) * kscale);
    s0.z = f2bf((aK0[2] + bk[q * 4 + 2]) * kscale);
    s0.w = f2bf((aK0[3] + bk[q * 4 + 3]) * kscale);
    s1.x = f2bf((aK1[0] + bk[16 + q * 4 + 0]) * kscale);
    s1.y = f2bf((aK1[1] + bk[16 + q * 4 + 1]) * kscale);
    s1.z = f2bf((aK1[2] + bk[16 + q * 4 + 2]) * kscale);
    s1.w = f2bf((aK1[3] + bk[16 + q * 4 + 3]) * kscale);
    *(short4*)(Kt + row + q * 4) = s0;
    *(short4*)(Kt + row + 16 + q * 4) = s1;
    union { hf16x2 h[2]; uint2 u; } p0, p1;
    p0.h[0] = __builtin_amdgcn_cvt_pkrtz(aV0[0] + bv[q * 4 + 0], aV0[1] + bv[q * 4 + 1]);
    p0.h[1] = __builtin_amdgcn_cvt_pkrtz(aV0[2] + bv[q * 4 + 2], aV0[3] + bv[q * 4 + 3]);
    p1.h[0] = __builtin_amdgcn_cvt_pkrtz(aV1[0] + bv[16 + q * 4 + 0], aV1[1] + bv[16 + q * 4 + 1]);
    p1.h[1] = __builtin_amdgcn_cvt_pkrtz(aV1[2] + bv[16 + q * 4 + 2], aV1[3] + bv[16 + q * 4 + 3]);
    *(uint2*)(Vt + row + q * 4) = p0.u;
    *(uint2*)(Vt + row + 16 + q * 4) = p1.u;
  } else {
    const int t = bid - 512;
    const int b = t >> 6;
    const int nt = ((t & 63) << 6) + (w << 4);
    bf16x8 ag = ld8(graph + ((size_t)b * NN + nt + lo) * 32 + q * 8);
    bf16x8 w0 = ld8(Wq + lo * 32 + q * 8);
    bf16x8 w1 = ld8(Wq + (lo + 16) * 32 + q * 8);
    f32x4 z = {0,0,0,0};
    f32x4 a0 = __builtin_amdgcn_mfma_f32_16x16x32_bf16(ag, w0, z, 0, 0, 0);
    f32x4 a1 = __builtin_amdgcn_mfma_f32_16x16x32_bf16(ag, w1, z, 0, 0, 0);
    const float b0 = bq[lo], b1 = bq[lo + 16];
    #pragma unroll
    for (int r = 0; r < 4; ++r) {
      const size_t rowq = ((size_t)b * NN + nt + q * 4 + r) * 32;
      Qb[rowq + lo] = f2bf(a0[r] + b0);
      Qb[rowq + 16 + lo] = f2bf(a1[r] + b1);
    }
  }
}

// ---------------------------------------------------------------------------
// Kernel B1: partial softmax denominators.  2048 blocks x 4 waves.
// Wave: 64 l x 256 n.  ALL 16 Q fragments issued upfront (16 outstanding
// 16B loads/lane -> one full-latency stall per wave instead of 16), then a
// fully unrolled MFMA -> exp2 consume stream.  Z += sum_n exp2 (atomicAdd).
// ---------------------------------------------------------------------------
__global__ __launch_bounds__(256, 4) void kb1_z(
    const short* __restrict__ Qb, const short* __restrict__ Kt,
    float* __restrict__ Z)
{
  const int tid = threadIdx.x;
  const int w = tid >> 6, lane = tid & 63, lo = lane & 15, q = lane >> 4;
  const int bid = blockIdx.x;
  const int b = bid >> 8;
  const int l0 = ((bid >> 2) & 63) << 6;
  const int nq = bid & 3;
  bf16x8 kf[4];
  #pragma unroll
  for (int f = 0; f < 4; ++f)
    kf[f] = *(const bf16x8*)(Kt + ((size_t)b * LL + l0 + f * 16 + lo) * 32 + q * 8);
  const short* qbase = Qb + ((size_t)b * NN + nq * 1024 + w * 256 + lo) * 32 + q * 8;
  bf16x8 qf[16];
  #pragma unroll
  for (int it = 0; it < 16; ++it)
    qf[it] = *(const bf16x8*)(qbase + it * 512);
  float za[4][4] = {{0}};
  #pragma unroll
  for (int it = 0; it < 16; ++it) {
    #pragma unroll
    for (int f = 0; f < 4; ++f) {
      f32x4 z = {0,0,0,0};
      f32x4 c = __builtin_amdgcn_mfma_f32_16x16x32_bf16(kf[f], qf[it], z, 0, 0, 0);
      #pragma unroll
      for (int r = 0; r < 4; ++r) za[f][r] += __builtin_amdgcn_exp2f(c[r]);
    }
  }
  // reduce over n (= lo, low 4 lane bits)
  #pragma unroll
  for (int m = 1; m < 16; m <<= 1)
    #pragma unroll
    for (int f = 0; f < 4; ++f)
      #pragma unroll
      for (int r = 0; r < 4; ++r)
        za[f][r] += __shfl_xor(za[f][r], m, 64);
  if (lo == 0) {
    #pragma unroll
    for (int f = 0; f < 4; ++f)
      #pragma unroll
      for (int r = 0; r < 4; ++r)
        atomicAdd(&Z[(size_t)b * LL + l0 + f * 16 + q * 4 + r], za[f][r]);
  }
}

// ---------------------------------------------------------------------------
// Kernel B2: Vpp[b][o][l] = Vt[b][l][o] * (4096 / Z_l)  (f16, [o][l] layout).
// ---------------------------------------------------------------------------
__global__ __launch_bounds__(256) void kb2_scale(
    const _Float16* __restrict__ Vt, const float* __restrict__ Z,
    _Float16* __restrict__ Vpp)
{
  const int tid = threadIdx.x;
  const int b = blockIdx.x >> 6;
  const int l = ((blockIdx.x & 63) << 6) + (tid & 63);
  const int og = tid >> 6;  // 0..3
  const float inv = __builtin_amdgcn_rcpf(Z[(size_t)b * LL + l]) * 4096.0f;
  const f16x8 vv = *(const f16x8*)(Vt + ((size_t)b * LL + l) * 32 + og * 8);
  #pragma unroll
  for (int j = 0; j < 8; ++j)
    Vpp[((size_t)b * 32 + og * 8 + j) * LL + l] = (_Float16)((float)vv[j] * inv);
}

// --------------------------- kc1 helpers -----------------------------------
__device__ __forceinline__ void load_kf(bf16x8 kf[4], const short* __restrict__ ktb,
                                        int lc) {
  #pragma unroll
  for (int f = 0; f < 4; ++f)
    kf[f] = *(const bf16x8*)(ktb + (size_t)(lc * 64 + f * 16) * 32);
}
__device__ __forceinline__ void load_v(f16x8 v[4], const _Float16* __restrict__ vb0,
                                       const _Float16* __restrict__ vb1, int lc, int q) {
  const int lbase = lc * 64;
  v[0] = *(const f16x8*)(vb0 + lbase + q * 8);
  v[1] = *(const f16x8*)(vb0 + lbase + 32 + q * 8);
  v[2] = *(const f16x8*)(vb1 + lbase + q * 8);
  v[3] = *(const f16x8*)(vb1 + lbase + 32 + q * 8);
}
__device__ __forceinline__ void compute_P(const bf16x8 kf[4], bf16x8 qf0, bf16x8 qf1,
                                          _Float16* __restrict__ Pb, int lo, int q) {
  #pragma unroll
  for (int f = 0; f < 4; ++f) {
    f32x4 z = {0,0,0,0};
    f32x4 c0 = __builtin_amdgcn_mfma_f32_16x16x32_bf16(kf[f], qf0, z, 0, 0, 0);
    f32x4 c1 = __builtin_amdgcn_mfma_f32_16x16x32_bf16(kf[f], qf1, z, 0, 0, 0);
    union { hf16x2 h[2]; uint2 u; } pk0, pk1;
    pk0.h[0] = __builtin_amdgcn_cvt_pkrtz(__builtin_amdgcn_exp2f(c0[0]),
                                          __builtin_amdgcn_exp2f(c0[1]));
    pk0.h[1] = __builtin_amdgcn_cvt_pkrtz(__builtin_amdgcn_exp2f(c0[2]),
                                          __builtin_amdgcn_exp2f(c0[3]));
    pk1.h[0] = __builtin_amdgcn_cvt_pkrtz(__builtin_amdgcn_exp2f(c1[0]),
                                          __builtin_amdgcn_exp2f(c1[1]));
    pk1.h[1] = __builtin_amdgcn_cvt_pkrtz(__builtin_amdgcn_exp2f(c1[2]),
                                          __builtin_amdgcn_exp2f(c1[3]));
    *(uint2*)&Pb[lo * 72 + f * 16 + q * 4] = pk0.u;
    *(uint2*)&Pb[(16 + lo) * 72 + f * 16 + q * 4] = pk1.u;
  }
}

// ---------------------------------------------------------------------------
// Kernel C1: message partials.  2048 blocks = (b, l-half, 32 n); wave covers
// 8 chunks of 64 l.  2-stage pipeline: P double-buffered in per-wave LDS,
// Kt prefetched 2 chunks ahead, V prefetched 1 chunk ahead — every load has
// >=1 chunk (~300 cy) of independent work before its first use.
// ---------------------------------------------------------------------------
__global__ __launch_bounds__(256, 4) void kc1_attn(
    const short* __restrict__ Qb, const short* __restrict__ Kt,
    const _Float16* __restrict__ Vpp, float* __restrict__ msgpart)
{
  __shared__ __align__(16) unsigned char smem[36864];   // 4 waves x 2 x 4608
  const int tid = threadIdx.x;
  const int w = tid >> 6, lane = tid & 63, lo = lane & 15, q = lane >> 4;
  const int bid = blockIdx.x;
  const int b = bid >> 8;
  const int half = (bid >> 7) & 1;
  const int n0 = (bid & 127) << 5;
  _Float16* const Pb0 = (_Float16*)(smem + w * 9216);
  _Float16* const Pb1 = Pb0 + 32 * 72;
  const bf16x8 qf0 = *(const bf16x8*)(Qb + ((size_t)b * NN + n0 + lo) * 32 + q * 8);
  const bf16x8 qf1 = *(const bf16x8*)(Qb + ((size_t)b * NN + n0 + 16 + lo) * 32 + q * 8);
  f32x4 m00 = {0,0,0,0}, m01 = {0,0,0,0}, m10 = {0,0,0,0}, m11 = {0,0,0,0};
  const short* ktb = Kt + (size_t)b * LL * 32 + lo * 32 + q * 8;
  const _Float16* vb0 = Vpp + ((size_t)b * 32 + lo) * LL;
  const _Float16* vb1 = vb0 + (size_t)16 * LL;
  const int lc0 = half * 32 + w * 8;
  bf16x8 kfs[2][4];
  f16x8 vs[2][4];
  load_kf(kfs[0], ktb, lc0);
  load_kf(kfs[1], ktb, lc0 + 1);
  load_v(vs[0], vb0, vb1, lc0, q);
  compute_P(kfs[0], qf0, qf1, Pb0, lo, q);   // P[0] -> buf0
  #pragma unroll
  for (int i = 0; i < 8; ++i) {
    _Float16* const bufC = (i & 1) ? Pb1 : Pb0;
    _Float16* const bufN = (i & 1) ? Pb0 : Pb1;
    // 1) A-fragment reads for chunk i (latency hidden by step 3)
    f16x8 pa00 = *(const f16x8*)&bufC[lo * 72 + q * 8];
    f16x8 pa01 = *(const f16x8*)&bufC[lo * 72 + 32 + q * 8];
    f16x8 pa10 = *(const f16x8*)&bufC[(16 + lo) * 72 + q * 8];
    f16x8 pa11 = *(const f16x8*)&bufC[(16 + lo) * 72 + 32 + q * 8];
    // 2) global prefetches: V for chunk i+1, Kt for chunk i+2
    if (i + 1 <= 7) load_v(vs[(i + 1) & 1], vb0, vb1, lc0 + i + 1, q);
    if (i + 2 <= 7) load_kf(kfs[i & 1], ktb, lc0 + i + 2);
    // 3) compute P[i+1] into the other buffer (long issue stream)
    if (i + 1 <= 7) compute_P(kfs[1 - (i & 1)], qf0, qf1, bufN, lo, q);
    // 4) message MFMAs for chunk i
    const f16x8* vc = vs[i & 1];
    m00 = __builtin_amdgcn_mfma_f32_16x16x32_f16(pa00, vc[0], m00, 0, 0, 0);
    m10 = __builtin_amdgcn_mfma_f32_16x16x32_f16(pa10, vc[0], m10, 0, 0, 0);
    m01 = __builtin_amdgcn_mfma_f32_16x16x32_f16(pa00, vc[2], m01, 0, 0, 0);
    m11 = __builtin_amdgcn_mfma_f32_16x16x32_f16(pa10, vc[2], m11, 0, 0, 0);
    m00 = __builtin_amdgcn_mfma_f32_16x16x32_f16(pa01, vc[1], m00, 0, 0, 0);
    m10 = __builtin_amdgcn_mfma_f32_16x16x32_f16(pa11, vc[1], m10, 0, 0, 0);
    m01 = __builtin_amdgcn_mfma_f32_16x16x32_f16(pa01, vc[3], m01, 0, 0, 0);
    m11 = __builtin_amdgcn_mfma_f32_16x16x32_f16(pa11, vc[3], m11, 0, 0, 0);
  }
  // stash msg partials into this wave's own P region (its P reads are done)
  float* MSw = (float*)(smem + w * 9216);   // [32 n][36]
  #pragma unroll
  for (int r = 0; r < 4; ++r) {
    MSw[(q * 4 + r) * 36 + lo] = m00[r];
    MSw[(q * 4 + r) * 36 + 16 + lo] = m01[r];
    MSw[(16 + q * 4 + r) * 36 + lo] = m10[r];
    MSw[(16 + q * 4 + r) * 36 + 16 + lo] = m11[r];
  }
  __syncthreads();
  // block-reduce the 4 wave partials, store 32x32 f32 tile (no atomics)
  const int nl = tid >> 3, oq = (tid & 7) << 2;
  f32x4 s = *(const f32x4*)((float*)(smem + 0 * 9216) + nl * 36 + oq);
  s += *(const f32x4*)((float*)(smem + 1 * 9216) + nl * 36 + oq);
  s += *(const f32x4*)((float*)(smem + 2 * 9216) + nl * 36 + oq);
  s += *(const f32x4*)((float*)(smem + 3 * 9216) + nl * 36 + oq);
  *(f32x4*)(msgpart + (((size_t)half * BB + b) * NN + n0 + nl) * 32 + oq) = s;
}

// ---------------------------------------------------------------------------
// Kernel C2: out[b][n][o] = graph + bc[o] + (Wc @ (mp0+mp1)[n])/4096.
// ---------------------------------------------------------------------------
__global__ __launch_bounds__(256) void kc2_out(
    const float* __restrict__ msgpart, const float* __restrict__ graph,
    const float* __restrict__ Wc, const float* __restrict__ bc,
    float* __restrict__ out)
{
  const int tid = threadIdx.x;
  const int b = blockIdx.x >> 7;
  const int n = ((blockIdx.x & 127) << 5) + (tid >> 3);
  const int oq = (tid & 7) << 2;
  const float* mp0 = msgpart + ((size_t)b * NN + n) * 32;
  const float* mp1 = msgpart + ((size_t)(BB + b) * NN + n) * 32;
  float m[32];
  #pragma unroll
  for (int c4 = 0; c4 < 8; ++c4) {
    f32x4 a = *(const f32x4*)(mp0 + c4 * 4);
    f32x4 bsum = *(const f32x4*)(mp1 + c4 * 4);
    f32x4 s = a + bsum;
    m[c4 * 4 + 0] = s[0]; m[c4 * 4 + 1] = s[1];
    m[c4 * 4 + 2] = s[2]; m[c4 * 4 + 3] = s[3];
  }
  #pragma unroll
  for (int j = 0; j < 4; ++j) {
    const int o = oq + j;
    float acc = 0.0f;
    #pragma unroll
    for (int c4 = 0; c4 < 8; ++c4) {
      f32x4 wv = *(const f32x4*)(Wc + o * 32 + c4 * 4);
      acc += wv[0] * m[c4 * 4 + 0] + wv[1] * m[c4 * 4 + 1]
           + wv[2] * m[c4 * 4 + 2] + wv[3] * m[c4 * 4 + 3];
    }
    const size_t idx = ((size_t)b * NN + n) * 32 + o;
    out[idx] = acc * (1.0f / 4096.0f) + bc[o] + graph[idx];
  }
}

// ---------------------------------------------------------------------------
extern "C" void kernel_launch(void* const* d_in, const int* in_sizes, int n_in,
                              void* d_out, int out_size, void* d_ws, size_t ws_size,
                              hipStream_t stream) {
  const float* graph = (const float*)d_in[0];
  const float* img   = (const float*)d_in[1];
  const float* Wq    = (const float*)d_in[2];
  const float* bq    = (const float*)d_in[3];
  const float* Wk    = (const float*)d_in[4];
  const float* bk    = (const float*)d_in[5];
  const float* Wv    = (const float*)d_in[6];
  const float* bv    = (const float*)d_in[7];
  const float* Wc    = (const float*)d_in[8];
  const float* bc    = (const float*)d_in[9];
  char* ws = (char*)d_ws;
  short*    Qb  = (short*)(ws + 0);          // 2 MB   bf16 [B][N][32]
  short*    Kt  = (short*)(ws + 2097152);    // 2 MB   bf16 [B][L][32] (scaled)
  _Float16* Vt  = (_Float16*)(ws + 4194304); // 2 MB   f16  [B][L][32]
  _Float16* Vpp = (_Float16*)(ws + 6291456); // 2 MB   f16  [B][32][L] (V*4096/Z)
  float*    Zb  = (float*)(ws + 8388608);    // 128 KB f32  [B][L]
  float*    Mp  = (float*)(ws + 8519680);    // 8 MB   f32  [2][B][N][32]
  ka_proj<<<dim3(1024), dim3(256), 0, stream>>>(graph, img, Wq, bq, Wk, bk, Wv, bv,
                                                Qb, Kt, Vt, Zb);
  kb1_z<<<dim3(2048), dim3(256), 0, stream>>>(Qb, Kt, Zb);
  kb2_scale<<<dim3(512), dim3(256), 0, stream>>>(Vt, Zb, Vpp);
  kc1_attn<<<dim3(2048), dim3(256), 0, stream>>>(Qb, Kt, Vpp, Mp);
  kc2_out<<<dim3(1024), dim3(256), 0, stream>>>(Mp, graph, Wc, bc, (float*)d_out);
}